// Round 1
// baseline (205.824 us; speedup 1.0000x reference)
//
#include <hip/hip_runtime.h>
#include <stdint.h>

#define BB 64
#define TT 512
#define HH 768
#define KK 4

// ---------------------------------------------------------------------------
// Kernel 1: emissions[b*T*K + t*K + k] = dot(sent[b,t,:], W[k,:]) + bias[k]
// Wave per (b,t) row. Lane l: k = l&3, slice = l>>2 (48 floats of H each).
// Reduce across 16 slices with shfl_xor 4/8/16/32 (k bits 0..1 untouched).
// ---------------------------------------------------------------------------
__global__ __launch_bounds__(256) void emis_kernel(
    const float* __restrict__ sent, const float* __restrict__ W,
    const float* __restrict__ bias, float* __restrict__ emis) {
  const int lane  = threadIdx.x & 63;
  const int wave  = threadIdx.x >> 6;
  const int gwave = blockIdx.x * 4 + wave;   // 0..8191
  const int k     = lane & 3;
  const int slice = lane >> 2;               // 0..15

  // preload this lane's W slice: W[k][slice*48 .. slice*48+47], 12 float4
  const float4* Wv = (const float4*)W;
  float4 w[12];
#pragma unroll
  for (int u = 0; u < 12; ++u) w[u] = Wv[k * 192 + slice * 12 + u];
  const float bk = bias[k];

#pragma unroll
  for (int i = 0; i < 4; ++i) {
    const int row = gwave + 8192 * i;        // 0..32767  (= b*T + t)
    const float4* sv = (const float4*)(sent + (size_t)row * HH);
    float a = 0.f;
#pragma unroll
    for (int u = 0; u < 12; ++u) {
      float4 x = sv[slice * 12 + u];
      a = fmaf(x.x, w[u].x, a);
      a = fmaf(x.y, w[u].y, a);
      a = fmaf(x.z, w[u].z, a);
      a = fmaf(x.w, w[u].w, a);
    }
    // reduce across slices (bits 2..5 of lane), k untouched
    a += __shfl_xor(a, 4);
    a += __shfl_xor(a, 8);
    a += __shfl_xor(a, 16);
    a += __shfl_xor(a, 32);
    if (lane < 4) emis[row * 4 + k] = a + bk;
  }
}

// ---------------------------------------------------------------------------
// Kernel 2: Viterbi per batch. 64 threads (1 wave) per block, block = batch.
// Scores replicated per quad: lane j = lane&3 holds score[j]; other three via
// DPP quad_perm rotations (pure VALU, no LDS in the chain).
// ---------------------------------------------------------------------------
template <int CTRL>
__device__ __forceinline__ float qperm(float x) {
  return __int_as_float(__builtin_amdgcn_update_dpp(
      0, __float_as_int(x), CTRL, 0xF, 0xF, true));
}

// compose packed 2-bit maps: h(x) = f(g(x))
__device__ __forceinline__ uint32_t map_compose(uint32_t f, uint32_t g) {
  uint32_t h = 0;
#pragma unroll
  for (int x = 0; x < 4; ++x) {
    uint32_t gx = (g >> (2 * x)) & 3u;
    uint32_t fx = (f >> (2 * gx)) & 3u;
    h |= fx << (2 * x);
  }
  return h;
}

__global__ __launch_bounds__(64) void viterbi_kernel(
    const float* __restrict__ emis, const float* __restrict__ trans,
    const float* __restrict__ startT, const float* __restrict__ endT,
    int* __restrict__ out) {
  const int b    = blockIdx.x;
  const int lane = threadIdx.x;          // 0..63
  const int j    = lane & 3;

  __shared__ uint8_t bp[4][520];         // bp[j][t]; 520 pad -> distinct banks per j

  const int i1 = (j + 1) & 3, i2 = (j + 2) & 3, i3 = (j + 3) & 3;
  const float tr0 = trans[j * 4 + j];
  const float tr1 = trans[i1 * 4 + j];
  const float tr2 = trans[i2 * 4 + j];
  const float tr3 = trans[i3 * 4 + j];

  const float* eb = emis + b * (TT * KK);
  float s = startT[j] + eb[j];           // t = 0

  auto step = [&](int t, float e) {
    float s1 = qperm<0x39>(s);           // score[(j+1)&3]
    float s2 = qperm<0x4E>(s);           // score[(j+2)&3]
    float s3 = qperm<0x93>(s);           // score[(j+3)&3]
    float c0 = s + tr0;
    float c1 = s1 + tr1;
    float c2 = s2 + tr2;
    float c3 = s3 + tr3;
    float m = c0; int bi = j;
    if (c1 > m) { m = c1; bi = i1; }
    if (c2 > m) { m = c2; bi = i2; }
    if (c3 > m) { m = c3; bi = i3; }
    s = m + e;
    if (lane < 4) bp[j][t] = (uint8_t)bi;
  };

  // software-pipelined forward pass: prefetch 8 emissions ahead
  float ebuf[8];
#pragma unroll
  for (int q = 0; q < 8; ++q) ebuf[q] = eb[(1 + q) * 4 + j];

  for (int c = 0; c < 63; ++c) {         // t = 8c+1 .. 8c+8
    float enext[8];
    const int base = 8 * c + 9;
#pragma unroll
    for (int q = 0; q < 8; ++q) {
      int tt = base + q; if (tt > 511) tt = 511;
      enext[q] = eb[tt * 4 + j];
    }
#pragma unroll
    for (int q = 0; q < 8; ++q) step(8 * c + 1 + q, ebuf[q]);
#pragma unroll
    for (int q = 0; q < 8; ++q) ebuf[q] = enext[q];
  }
#pragma unroll
  for (int q = 0; q < 7; ++q) step(505 + q, ebuf[q]);   // t = 505..511

  // final argmax over states (unique max -> identical on all lanes)
  float f = s + endT[j];
  {
    float f1 = qperm<0x39>(f);
    float f2 = qperm<0x4E>(f);
    float f3 = qperm<0x93>(f);
    float m = f; int bi = j;
    if (f1 > m) { m = f1; bi = i1; }
    if (f2 > m) { m = f2; bi = i2; }
    if (f3 > m) { m = f3; bi = i3; }
    f = (float)bi;                       // reuse f as carrier
  }
  const int best_last = (int)f;

  __syncthreads();

  // ---- backtrack via map composition ----
  // step s in [1,511]: map g_s(x) = bp[x][s]  (tag_s -> tag_{s-1})
  // lane l owns s in [8l+1, min(8l+8,511)]
  const int lo = 8 * lane + 1;
  uint32_t g[8];
  uint32_t A = 0xE4;                     // identity map
#pragma unroll
  for (int q = 7; q >= 0; --q) {
    const int sq = lo + q;
    uint32_t mq = 0xE4;
    if (sq <= 511) {
      mq = (uint32_t)bp[0][sq] | ((uint32_t)bp[1][sq] << 2) |
           ((uint32_t)bp[2][sq] << 4) | ((uint32_t)bp[3][sq] << 6);
    }
    g[q] = mq;
    A = map_compose(mq, A);              // apply later steps first
  }

  // inclusive suffix scan across lanes: V_l = G_l ∘ G_{l+1} ∘ ... ∘ G_63
  uint32_t V = A;
#pragma unroll
  for (int d = 1; d < 64; d <<= 1) {
    uint32_t o = __shfl_down(V, d);
    if (lane + d < 64) V = map_compose(V, o);
  }
  uint32_t S = __shfl_down(V, 1);        // exclusive (chunks above this lane)
  if (lane == 63) S = 0xE4;

  int cur = (int)((S >> (2 * best_last)) & 3u);   // tag at position hi
  const int hi = min(lo + 7, 511);
  int* ob = out + b * TT;
  ob[hi] = cur;
#pragma unroll
  for (int q = 7; q >= 0; --q) {
    const int sq = lo + q;
    if (sq <= 511) {
      cur = (int)((g[q] >> (2 * cur)) & 3u);
      ob[sq - 1] = cur;
    }
  }
}

extern "C" void kernel_launch(void* const* d_in, const int* in_sizes, int n_in,
                              void* d_out, int out_size, void* d_ws, size_t ws_size,
                              hipStream_t stream) {
  const float* sent   = (const float*)d_in[0];  // [B,T,H]
  const float* W      = (const float*)d_in[1];  // [K,H]
  const float* bias   = (const float*)d_in[2];  // [K]
  const float* startT = (const float*)d_in[3];  // [K]
  const float* endT   = (const float*)d_in[4];  // [K]
  const float* trans  = (const float*)d_in[5];  // [K,K]
  float* emis = (float*)d_ws;                   // [B,T,K] = 512 KB scratch
  int* outp   = (int*)d_out;                    // [B,T] int32

  emis_kernel<<<2048, 256, 0, stream>>>(sent, W, bias, emis);
  viterbi_kernel<<<BB, 64, 0, stream>>>(emis, trans, startT, endT, outp);
}

// Round 2
// 175.436 us; speedup vs baseline: 1.1732x; 1.1732x over previous
//
#include <hip/hip_runtime.h>
#include <stdint.h>

#define BB 64
#define TT 512
#define HH 768
#define KK 4

template <int CTRL>
__device__ __forceinline__ float dppf(float x) {
  return __int_as_float(__builtin_amdgcn_update_dpp(
      0, __float_as_int(x), CTRL, 0xF, 0xF, true));
}

// ---------------------------------------------------------------------------
// Kernel 1: emissions[row*4+k] = dot(sent[row,:], W[k,:]) + bias[k]
// Wave per row; lane l owns float4 #l of each 1KB chunk (3 chunks of 256
// floats). Fully coalesced 1KB per load instruction. 4 accumulators/lane.
// Reduction: DPP row_ror4/ror8 + quad xor1/xor2 (within 16), then
// shfl_xor 16/32. Lane 0 stores float4.
// ---------------------------------------------------------------------------
__global__ __launch_bounds__(256) void emis_kernel(
    const float* __restrict__ sent, const float* __restrict__ W,
    const float* __restrict__ bias, float* __restrict__ emis) {
  const int lane  = threadIdx.x & 63;
  const int wave  = threadIdx.x >> 6;
  const int gwave = blockIdx.x * 4 + wave;   // 0..4095

  const float4* Wv = (const float4*)W;
  float4 w[4][3];
#pragma unroll
  for (int k = 0; k < 4; ++k)
#pragma unroll
    for (int c = 0; c < 3; ++c) w[k][c] = Wv[k * 192 + c * 64 + lane];

  const float4 bb = ((const float4*)bias)[0];
  const float4* sv = (const float4*)sent;

  int row = gwave * 8;
  float4 x[3];
#pragma unroll
  for (int c = 0; c < 3; ++c) x[c] = sv[(size_t)row * 192 + c * 64 + lane];

#pragma unroll
  for (int it = 0; it < 8; ++it) {
    float4 xn[3];
    if (it < 7) {
#pragma unroll
      for (int c = 0; c < 3; ++c)
        xn[c] = sv[(size_t)(row + 1) * 192 + c * 64 + lane];
    }
    float a0 = 0.f, a1 = 0.f, a2 = 0.f, a3 = 0.f;
#pragma unroll
    for (int c = 0; c < 3; ++c) {
      a0 = fmaf(x[c].x, w[0][c].x, a0); a0 = fmaf(x[c].y, w[0][c].y, a0);
      a0 = fmaf(x[c].z, w[0][c].z, a0); a0 = fmaf(x[c].w, w[0][c].w, a0);
      a1 = fmaf(x[c].x, w[1][c].x, a1); a1 = fmaf(x[c].y, w[1][c].y, a1);
      a1 = fmaf(x[c].z, w[1][c].z, a1); a1 = fmaf(x[c].w, w[1][c].w, a1);
      a2 = fmaf(x[c].x, w[2][c].x, a2); a2 = fmaf(x[c].y, w[2][c].y, a2);
      a2 = fmaf(x[c].z, w[2][c].z, a2); a2 = fmaf(x[c].w, w[2][c].w, a2);
      a3 = fmaf(x[c].x, w[3][c].x, a3); a3 = fmaf(x[c].y, w[3][c].y, a3);
      a3 = fmaf(x[c].z, w[3][c].z, a3); a3 = fmaf(x[c].w, w[3][c].w, a3);
    }
    // within-16 reduction: ror4, ror8, quad xor1 (0xB1), quad xor2 (0x4E)
#define RED16(a)                                                   \
    a += dppf<0x124>(a); a += dppf<0x128>(a);                      \
    a += dppf<0xB1>(a);  a += dppf<0x4E>(a);
    RED16(a0) RED16(a1) RED16(a2) RED16(a3)
#undef RED16
    a0 += __shfl_xor(a0, 16); a0 += __shfl_xor(a0, 32);
    a1 += __shfl_xor(a1, 16); a1 += __shfl_xor(a1, 32);
    a2 += __shfl_xor(a2, 16); a2 += __shfl_xor(a2, 32);
    a3 += __shfl_xor(a3, 16); a3 += __shfl_xor(a3, 32);
    if (lane == 0) {
      float4 o; o.x = a0 + bb.x; o.y = a1 + bb.y; o.z = a2 + bb.z; o.w = a3 + bb.w;
      ((float4*)emis)[row] = o;
    }
    row += 1;
#pragma unroll
    for (int c = 0; c < 3; ++c) x[c] = xn[c];
  }
}

// ---------------------------------------------------------------------------
// Kernel 2: Viterbi per batch. 1 wave per block, block = batch.
// Forward chain: quad-broadcast DPP -> add -> max3/max -> add e (no argmax
// on the chain). Scores for every t stored to LDS; backpointers recomputed
// lane-parallel afterwards with exact lowest-index argmax semantics, then
// backtrack via 2-bit map composition suffix scan.
// ---------------------------------------------------------------------------

// compose packed 2-bit maps: h(x) = f(g(x))
__device__ __forceinline__ uint32_t map_compose(uint32_t f, uint32_t g) {
  uint32_t h = 0;
#pragma unroll
  for (int x = 0; x < 4; ++x) {
    uint32_t gx = (g >> (2 * x)) & 3u;
    uint32_t fx = (f >> (2 * gx)) & 3u;
    h |= fx << (2 * x);
  }
  return h;
}

__global__ __launch_bounds__(64) void viterbi_kernel(
    const float* __restrict__ emis, const float* __restrict__ trans,
    const float* __restrict__ startT, const float* __restrict__ endT,
    int* __restrict__ out) {
  const int b    = blockIdx.x;
  const int lane = threadIdx.x;          // 0..63
  const int j    = lane & 3;

  __shared__ float sc[TT][4];            // post-update scores, 8 KB

  const float tr0 = trans[0 * 4 + j];
  const float tr1 = trans[1 * 4 + j];
  const float tr2 = trans[2 * 4 + j];
  const float tr3 = trans[3 * 4 + j];

  const float* eb = emis + b * (TT * KK);
  float s = startT[j] + eb[j];           // t = 0
  if (lane < 4) sc[0][j] = s;

  auto step = [&](int t, float e) {
    float v0 = dppf<0x00>(s);            // s_prev[0]
    float v1 = dppf<0x55>(s);            // s_prev[1]
    float v2 = dppf<0xAA>(s);            // s_prev[2]
    float v3 = dppf<0xFF>(s);            // s_prev[3]
    float c0 = v0 + tr0;
    float c1 = v1 + tr1;
    float c2 = v2 + tr2;
    float c3 = v3 + tr3;
    float m = fmaxf(fmaxf(c0, c1), fmaxf(c2, c3));
    s = m + e;
    if (lane < 4) sc[t][j] = s;
  };

  // software-pipelined forward pass: prefetch 8 emissions ahead
  float ebuf[8];
#pragma unroll
  for (int q = 0; q < 8; ++q) ebuf[q] = eb[(1 + q) * 4 + j];

  for (int c = 0; c < 63; ++c) {         // t = 8c+1 .. 8c+8
    float enext[8];
    const int base = 8 * c + 9;
#pragma unroll
    for (int q = 0; q < 8; ++q) {
      int tt = base + q; if (tt > 511) tt = 511;
      enext[q] = eb[tt * 4 + j];
    }
#pragma unroll
    for (int q = 0; q < 8; ++q) step(8 * c + 1 + q, ebuf[q]);
#pragma unroll
    for (int q = 0; q < 8; ++q) ebuf[q] = enext[q];
  }
#pragma unroll
  for (int q = 0; q < 7; ++q) step(505 + q, ebuf[q]);   // t = 505..511

  // final argmax, exact lowest-index tie-break (all lanes agree)
  float f = s + endT[j];
  int best_last;
  {
    float f0 = dppf<0x00>(f);
    float f1 = dppf<0x55>(f);
    float f2 = dppf<0xAA>(f);
    float f3 = dppf<0xFF>(f);
    float bm = f0; int bi = 0;
    if (f1 > bm) { bm = f1; bi = 1; }
    if (f2 > bm) { bm = f2; bi = 2; }
    if (f3 > bm) { bm = f3; bi = 3; }
    best_last = bi;
  }

  __syncthreads();

  // uniform transition matrix for recompute (scalar loads)
  float t16[16];
#pragma unroll
  for (int i = 0; i < 16; ++i) t16[i] = trans[i];

  // recompute backpointer maps lane-parallel:
  // step sq in [1,511]: g(x) = argmax_i(sc[sq-1][i] + trans[i][x])
  const int lo = 8 * lane + 1;
  uint32_t g[8];
  uint32_t A = 0xE4;                     // identity map
#pragma unroll
  for (int q = 7; q >= 0; --q) {
    const int sq = lo + q;
    uint32_t mq = 0xE4;
    if (sq <= 511) {
      const float4 pv = *((const float4*)sc[sq - 1]);
      mq = 0;
#pragma unroll
      for (int j2 = 0; j2 < 4; ++j2) {
        float c0 = pv.x + t16[0 * 4 + j2];
        float c1 = pv.y + t16[1 * 4 + j2];
        float c2 = pv.z + t16[2 * 4 + j2];
        float c3 = pv.w + t16[3 * 4 + j2];
        float bm = c0; uint32_t bi = 0;
        if (c1 > bm) { bm = c1; bi = 1; }
        if (c2 > bm) { bm = c2; bi = 2; }
        if (c3 > bm) { bm = c3; bi = 3; }
        mq |= bi << (2 * j2);
      }
    }
    g[q] = mq;
    A = map_compose(mq, A);              // later steps applied first
  }

  // inclusive suffix scan across lanes: V_l = G_l ∘ G_{l+1} ∘ ... ∘ G_63
  uint32_t V = A;
#pragma unroll
  for (int d = 1; d < 64; d <<= 1) {
    uint32_t o = __shfl_down(V, d);
    if (lane + d < 64) V = map_compose(V, o);
  }
  uint32_t S = __shfl_down(V, 1);        // exclusive (chunks above this lane)
  if (lane == 63) S = 0xE4;

  int cur = (int)((S >> (2 * best_last)) & 3u);   // tag at position hi
  const int hi = min(lo + 7, 511);
  int* ob = out + b * TT;
  ob[hi] = cur;
#pragma unroll
  for (int q = 7; q >= 0; --q) {
    const int sq = lo + q;
    if (sq <= 511) {
      cur = (int)((g[q] >> (2 * cur)) & 3u);
      ob[sq - 1] = cur;
    }
  }
}

extern "C" void kernel_launch(void* const* d_in, const int* in_sizes, int n_in,
                              void* d_out, int out_size, void* d_ws, size_t ws_size,
                              hipStream_t stream) {
  const float* sent   = (const float*)d_in[0];  // [B,T,H]
  const float* W      = (const float*)d_in[1];  // [K,H]
  const float* bias   = (const float*)d_in[2];  // [K]
  const float* startT = (const float*)d_in[3];  // [K]
  const float* endT   = (const float*)d_in[4];  // [K]
  const float* trans  = (const float*)d_in[5];  // [K,K]
  float* emis = (float*)d_ws;                   // [B,T,K] = 512 KB scratch
  int* outp   = (int*)d_out;                    // [B,T] int32

  emis_kernel<<<1024, 256, 0, stream>>>(sent, W, bias, emis);
  viterbi_kernel<<<BB, 64, 0, stream>>>(emis, trans, startT, endT, outp);
}